// Round 1
// baseline (30.254 us; speedup 1.0000x reference)
//
#include <hip/hip_runtime.h>
#include <math.h>

// Problem constants (from reference): B=1024, IN_DIM=4096, OUT_DIM=4096, FAN_IN=8
#define BDIM 1024
#define IN_DIM 4096
#define OUT_DIM 4096
#define FAN_IN 8
#define NTHREADS 256
#define OUTS_PER_THREAD (OUT_DIM / NTHREADS)   // 16

__global__ __launch_bounds__(NTHREADS) void WeightedThresholdGate_53085795778563_kernel(
    const float* __restrict__ x,      // [B, IN_DIM]
    const int*   __restrict__ idx,    // [OUT_DIM, FAN_IN]
    const float* __restrict__ w,      // [OUT_DIM, FAN_IN]
    const float* __restrict__ theta,  // [OUT_DIM]
    const float* __restrict__ s_raw,  // [OUT_DIM]
    float*       __restrict__ out)    // [B, OUT_DIM]
{
    __shared__ float xrow[IN_DIM];    // 16 KiB

    const int b = blockIdx.x;
    const int t = threadIdx.x;

    // Stage x[b, :] into LDS: 4096 floats via 256 threads x 4 float4 (coalesced)
    const float4* __restrict__ xsrc = reinterpret_cast<const float4*>(x + (size_t)b * IN_DIM);
    float4* xdst = reinterpret_cast<float4*>(xrow);
#pragma unroll
    for (int i = 0; i < IN_DIM / (4 * NTHREADS); ++i) {
        xdst[t + i * NTHREADS] = xsrc[t + i * NTHREADS];
    }
    __syncthreads();

    float* __restrict__ orow = out + (size_t)b * OUT_DIM;

#pragma unroll 4
    for (int i = 0; i < OUTS_PER_THREAD; ++i) {
        const int o = t + i * NTHREADS;

        // Vector-load idx[o][0..7] (32 B) and w[o][0..7] (32 B)
        const int4*   ip = reinterpret_cast<const int4*>(idx + (size_t)o * FAN_IN);
        const float4* wp = reinterpret_cast<const float4*>(w  + (size_t)o * FAN_IN);
        const int4   i0 = ip[0], i1 = ip[1];
        const float4 w0 = wp[0], w1 = wp[1];

        float z = 0.0f;
        z = fmaf(xrow[i0.x], w0.x, z);
        z = fmaf(xrow[i0.y], w0.y, z);
        z = fmaf(xrow[i0.z], w0.z, z);
        z = fmaf(xrow[i0.w], w0.w, z);
        z = fmaf(xrow[i1.x], w1.x, z);
        z = fmaf(xrow[i1.y], w1.y, z);
        z = fmaf(xrow[i1.z], w1.z, z);
        z = fmaf(xrow[i1.w], w1.w, z);
        z -= theta[o];

        // softplus(s_raw) + 1e-6, numerically stable: max(x,0) + log1p(exp(-|x|))
        const float sr = s_raw[o];
        const float sp = fmaxf(sr, 0.0f) + log1pf(expf(-fabsf(sr)));
        const float s  = sp + 1e-6f;

        // sigmoid(s * z)
        const float zz = s * z;
        orow[o] = 1.0f / (1.0f + expf(-zz));
    }
}

extern "C" void kernel_launch(void* const* d_in, const int* in_sizes, int n_in,
                              void* d_out, int out_size, void* d_ws, size_t ws_size,
                              hipStream_t stream) {
    const float* x     = (const float*)d_in[0];
    const int*   idx   = (const int*)  d_in[1];
    const float* w     = (const float*)d_in[2];
    const float* theta = (const float*)d_in[3];
    const float* s_raw = (const float*)d_in[4];
    float* out = (float*)d_out;

    dim3 grid(BDIM);
    dim3 block(NTHREADS);
    WeightedThresholdGate_53085795778563_kernel<<<grid, block, 0, stream>>>(
        x, idx, w, theta, s_raw, out);
}

// Round 2
// 18.698 us; speedup vs baseline: 1.6180x; 1.6180x over previous
//
#include <hip/hip_runtime.h>
#include <math.h>

// Problem constants: B=1024, IN_DIM=4096, OUT_DIM=4096, FAN_IN=8
#define BDIM 1024
#define IN_DIM 4096
#define OUT_DIM 4096
#define FAN_IN 8
#define NT 512
#define TILE_B 4
#define OPT (OUT_DIM / NT)   // 8 outputs per thread

__global__ __launch_bounds__(NT, 2) void WeightedThresholdGate_53085795778563_kernel(
    const float* __restrict__ x,      // [B, IN_DIM]
    const int*   __restrict__ idx,    // [OUT_DIM, FAN_IN]
    const float* __restrict__ w,      // [OUT_DIM, FAN_IN]
    const float* __restrict__ theta,  // [OUT_DIM]
    const float* __restrict__ s_raw,  // [OUT_DIM]
    float*       __restrict__ out)    // [B, OUT_DIM]
{
    // Transposed stage: xT[j][r] = x[b0+r][j], so one b128 read at index j
    // yields the gathered value for all 4 batch rows. 64 KiB.
    __shared__ __align__(16) float xT[IN_DIM * TILE_B];

    const int t  = threadIdx.x;
    const int b0 = blockIdx.x * TILE_B;

    // Staging: for fixed r, lanes read consecutive addresses (coalesced);
    // writes are lane-contiguous ds_write_b128 (conflict-free b128 pattern).
    for (int j = t; j < IN_DIM; j += NT) {
        float4 v;
        v.x = x[(size_t)(b0 + 0) * IN_DIM + j];
        v.y = x[(size_t)(b0 + 1) * IN_DIM + j];
        v.z = x[(size_t)(b0 + 2) * IN_DIM + j];
        v.w = x[(size_t)(b0 + 3) * IN_DIM + j];
        reinterpret_cast<float4*>(xT)[j] = v;
    }
    __syncthreads();

    const float4* __restrict__ xTv = reinterpret_cast<const float4*>(xT);

#pragma unroll 2
    for (int i = 0; i < OPT; ++i) {
        const int o = t + i * NT;

        const int4*   ip = reinterpret_cast<const int4*>(idx + (size_t)o * FAN_IN);
        const float4* wp = reinterpret_cast<const float4*>(w  + (size_t)o * FAN_IN);
        const int4   i0 = ip[0], i1 = ip[1];
        const float4 w0 = wp[0], w1 = wp[1];

        float4 acc = {0.f, 0.f, 0.f, 0.f};
        float4 xv;

        xv = xTv[i0.x];
        acc.x = fmaf(xv.x, w0.x, acc.x); acc.y = fmaf(xv.y, w0.x, acc.y);
        acc.z = fmaf(xv.z, w0.x, acc.z); acc.w = fmaf(xv.w, w0.x, acc.w);
        xv = xTv[i0.y];
        acc.x = fmaf(xv.x, w0.y, acc.x); acc.y = fmaf(xv.y, w0.y, acc.y);
        acc.z = fmaf(xv.z, w0.y, acc.z); acc.w = fmaf(xv.w, w0.y, acc.w);
        xv = xTv[i0.z];
        acc.x = fmaf(xv.x, w0.z, acc.x); acc.y = fmaf(xv.y, w0.z, acc.y);
        acc.z = fmaf(xv.z, w0.z, acc.z); acc.w = fmaf(xv.w, w0.z, acc.w);
        xv = xTv[i0.w];
        acc.x = fmaf(xv.x, w0.w, acc.x); acc.y = fmaf(xv.y, w0.w, acc.y);
        acc.z = fmaf(xv.z, w0.w, acc.z); acc.w = fmaf(xv.w, w0.w, acc.w);
        xv = xTv[i1.x];
        acc.x = fmaf(xv.x, w1.x, acc.x); acc.y = fmaf(xv.y, w1.x, acc.y);
        acc.z = fmaf(xv.z, w1.x, acc.z); acc.w = fmaf(xv.w, w1.x, acc.w);
        xv = xTv[i1.y];
        acc.x = fmaf(xv.x, w1.y, acc.x); acc.y = fmaf(xv.y, w1.y, acc.y);
        acc.z = fmaf(xv.z, w1.y, acc.z); acc.w = fmaf(xv.w, w1.y, acc.w);
        xv = xTv[i1.z];
        acc.x = fmaf(xv.x, w1.z, acc.x); acc.y = fmaf(xv.y, w1.z, acc.y);
        acc.z = fmaf(xv.z, w1.z, acc.z); acc.w = fmaf(xv.w, w1.z, acc.w);
        xv = xTv[i1.w];
        acc.x = fmaf(xv.x, w1.w, acc.x); acc.y = fmaf(xv.y, w1.w, acc.y);
        acc.z = fmaf(xv.z, w1.w, acc.z); acc.w = fmaf(xv.w, w1.w, acc.w);

        const float th = theta[o];
        const float sr = s_raw[o];
        // softplus computed once per (block, o) instead of per (b, o)
        const float sp = fmaxf(sr, 0.0f) + log1pf(expf(-fabsf(sr)));
        const float s  = sp + 1e-6f;

        // Coalesced dword stores per row
        out[(size_t)(b0 + 0) * OUT_DIM + o] = 1.0f / (1.0f + expf(-s * (acc.x - th)));
        out[(size_t)(b0 + 1) * OUT_DIM + o] = 1.0f / (1.0f + expf(-s * (acc.y - th)));
        out[(size_t)(b0 + 2) * OUT_DIM + o] = 1.0f / (1.0f + expf(-s * (acc.z - th)));
        out[(size_t)(b0 + 3) * OUT_DIM + o] = 1.0f / (1.0f + expf(-s * (acc.w - th)));
    }
}

extern "C" void kernel_launch(void* const* d_in, const int* in_sizes, int n_in,
                              void* d_out, int out_size, void* d_ws, size_t ws_size,
                              hipStream_t stream) {
    const float* x     = (const float*)d_in[0];
    const int*   idx   = (const int*)  d_in[1];
    const float* w     = (const float*)d_in[2];
    const float* theta = (const float*)d_in[3];
    const float* s_raw = (const float*)d_in[4];
    float* out = (float*)d_out;

    dim3 grid(BDIM / TILE_B);   // 256 blocks
    dim3 block(NT);             // 512 threads = 8 waves
    WeightedThresholdGate_53085795778563_kernel<<<grid, block, 0, stream>>>(
        x, idx, w, theta, s_raw, out);
}

// Round 4
// 15.380 us; speedup vs baseline: 1.9671x; 1.2158x over previous
//
#include <hip/hip_runtime.h>
#include <math.h>

// Problem constants: B=1024, IN_DIM=4096, OUT_DIM=4096, FAN_IN=8
#define BDIM 1024
#define IN_DIM 4096
#define OUT_DIM 4096
#define FAN_IN 8
#define NT 1024
#define TILE_B 4
#define OPT (OUT_DIM / NT)   // 4 outputs per thread

#define LOG2E 1.442695040888963f

__device__ __forceinline__ float fast_exp(float v) {
    return exp2f(v * LOG2E);   // v_exp_f32
}

__global__ __launch_bounds__(NT, 4) void WeightedThresholdGate_53085795778563_kernel(
    const float* __restrict__ x,      // [B, IN_DIM]
    const int*   __restrict__ idx,    // [OUT_DIM, FAN_IN]
    const float* __restrict__ w,      // [OUT_DIM, FAN_IN]
    const float* __restrict__ theta,  // [OUT_DIM]
    const float* __restrict__ s_raw,  // [OUT_DIM]
    float*       __restrict__ out)    // [B, OUT_DIM]
{
    // Transposed stage: xT[j][r] = x[b0+r][j]; one ds_read_b128 at index j
    // yields the gathered value for all 4 batch rows. 64 KiB.
    __shared__ __align__(16) float xT[IN_DIM * TILE_B];

    const int t  = threadIdx.x;
    const int b0 = blockIdx.x * TILE_B;

    // Staging: scalar global reads (each is a fully-coalesced wave access of
    // consecutive addresses within one row); ds_write_b128 lane-contiguous
    // (conflict-free: lanes 0..7 cover all 32 banks per phase).
#pragma unroll
    for (int k = 0; k < IN_DIM / NT; ++k) {
        const int j = t + k * NT;
        float4 v;
        v.x = x[(size_t)(b0 + 0) * IN_DIM + j];
        v.y = x[(size_t)(b0 + 1) * IN_DIM + j];
        v.z = x[(size_t)(b0 + 2) * IN_DIM + j];
        v.w = x[(size_t)(b0 + 3) * IN_DIM + j];
        reinterpret_cast<float4*>(xT)[j] = v;
    }
    __syncthreads();

    const float4* __restrict__ xTv = reinterpret_cast<const float4*>(xT);

#pragma unroll
    for (int i = 0; i < OPT; ++i) {
        const int o = t + i * NT;

        const int4*   ip = reinterpret_cast<const int4*>(idx + (size_t)o * FAN_IN);
        const float4* wp = reinterpret_cast<const float4*>(w  + (size_t)o * FAN_IN);
        const int4   i0 = ip[0], i1 = ip[1];
        const float4 w0 = wp[0], w1 = wp[1];

        float4 acc = {0.f, 0.f, 0.f, 0.f};
        float4 xv;

        xv = xTv[i0.x];
        acc.x = fmaf(xv.x, w0.x, acc.x); acc.y = fmaf(xv.y, w0.x, acc.y);
        acc.z = fmaf(xv.z, w0.x, acc.z); acc.w = fmaf(xv.w, w0.x, acc.w);
        xv = xTv[i0.y];
        acc.x = fmaf(xv.x, w0.y, acc.x); acc.y = fmaf(xv.y, w0.y, acc.y);
        acc.z = fmaf(xv.z, w0.y, acc.z); acc.w = fmaf(xv.w, w0.y, acc.w);
        xv = xTv[i0.z];
        acc.x = fmaf(xv.x, w0.z, acc.x); acc.y = fmaf(xv.y, w0.z, acc.y);
        acc.z = fmaf(xv.z, w0.z, acc.z); acc.w = fmaf(xv.w, w0.z, acc.w);
        xv = xTv[i0.w];
        acc.x = fmaf(xv.x, w0.w, acc.x); acc.y = fmaf(xv.y, w0.w, acc.y);
        acc.z = fmaf(xv.z, w0.w, acc.z); acc.w = fmaf(xv.w, w0.w, acc.w);
        xv = xTv[i1.x];
        acc.x = fmaf(xv.x, w1.x, acc.x); acc.y = fmaf(xv.y, w1.x, acc.y);
        acc.z = fmaf(xv.z, w1.x, acc.z); acc.w = fmaf(xv.w, w1.x, acc.w);
        xv = xTv[i1.y];
        acc.x = fmaf(xv.x, w1.y, acc.x); acc.y = fmaf(xv.y, w1.y, acc.y);
        acc.z = fmaf(xv.z, w1.y, acc.z); acc.w = fmaf(xv.w, w1.y, acc.w);
        xv = xTv[i1.z];
        acc.x = fmaf(xv.x, w1.z, acc.x); acc.y = fmaf(xv.y, w1.z, acc.y);
        acc.z = fmaf(xv.z, w1.z, acc.z); acc.w = fmaf(xv.w, w1.z, acc.w);
        xv = xTv[i1.w];
        acc.x = fmaf(xv.x, w1.w, acc.x); acc.y = fmaf(xv.y, w1.w, acc.y);
        acc.z = fmaf(xv.z, w1.w, acc.z); acc.w = fmaf(xv.w, w1.w, acc.w);

        const float th = theta[o];
        const float sr = s_raw[o];
        // softplus(sr) + 1e-6, stable: max(sr,0) + log1p(exp(-|sr|))
        const float sp = fmaxf(sr, 0.0f) + log1pf(fast_exp(-fabsf(sr)));
        const float s  = sp + 1e-6f;

        const float g0 = 1.0f / (1.0f + fast_exp(-s * (acc.x - th)));
        const float g1 = 1.0f / (1.0f + fast_exp(-s * (acc.y - th)));
        const float g2 = 1.0f / (1.0f + fast_exp(-s * (acc.z - th)));
        const float g3 = 1.0f / (1.0f + fast_exp(-s * (acc.w - th)));

        // Streamed output: nontemporal, keep L2 for idx/w broadcast reuse
        __builtin_nontemporal_store(g0, &out[(size_t)(b0 + 0) * OUT_DIM + o]);
        __builtin_nontemporal_store(g1, &out[(size_t)(b0 + 1) * OUT_DIM + o]);
        __builtin_nontemporal_store(g2, &out[(size_t)(b0 + 2) * OUT_DIM + o]);
        __builtin_nontemporal_store(g3, &out[(size_t)(b0 + 3) * OUT_DIM + o]);
    }
}

extern "C" void kernel_launch(void* const* d_in, const int* in_sizes, int n_in,
                              void* d_out, int out_size, void* d_ws, size_t ws_size,
                              hipStream_t stream) {
    const float* x     = (const float*)d_in[0];
    const int*   idx   = (const int*)  d_in[1];
    const float* w     = (const float*)d_in[2];
    const float* theta = (const float*)d_in[3];
    const float* s_raw = (const float*)d_in[4];
    float* out = (float*)d_out;

    dim3 grid(BDIM / TILE_B);   // 256 blocks, 1 per CU
    dim3 block(NT);             // 1024 threads = 16 waves = 4/SIMD
    WeightedThresholdGate_53085795778563_kernel<<<grid, block, 0, stream>>>(
        x, idx, w, theta, s_raw, out);
}